// Round 12
// baseline (294.631 us; speedup 1.0000x reference)
//
#include <hip/hip_runtime.h>
#include <hip/hip_bf16.h>

#define NSLOPE 0.2f
#define MAXDEG 64

typedef short bf16x8 __attribute__((ext_vector_type(8)));
typedef float f32x4 __attribute__((ext_vector_type(4)));

__device__ __forceinline__ unsigned short f2b(float f) {
    unsigned u = __float_as_uint(f);
    unsigned r = (u + 0x7FFFu + ((u >> 16) & 1u)) >> 16;
    return (unsigned short)r;
}
__device__ __forceinline__ float b2f_lo(unsigned w) {
    return __uint_as_float(w << 16);
}
__device__ __forceinline__ float b2f_hi(unsigned w) {
    return __uint_as_float(w & 0xFFFF0000u);
}
__device__ __forceinline__ float b2f_s(short s) {
    return __uint_as_float(((unsigned)(unsigned short)s) << 16);
}
__device__ __forceinline__ unsigned packb(float lo, float hi) {
    return ((unsigned)f2b(hi) << 16) | (unsigned)f2b(lo);
}

// ---------------- tiny prep: deg zero + score-weight dots + biases ----------
__global__ __launch_bounds__(256) void prep_small(
    const float* __restrict__ W0, const float* __restrict__ W1,
    const float* __restrict__ W2, const float* __restrict__ W3,
    const float* __restrict__ a_src, const float* __restrict__ a_dst,
    const float* __restrict__ gat_b, const float* __restrict__ res_b,
    const float* __restrict__ linB0, float* __restrict__ wsd0,
    float* __restrict__ wsdL, float* __restrict__ bias128,
    float* __restrict__ gb0res, int* __restrict__ deg, int n) {
    const int bx = blockIdx.x;
    const int tid = threadIdx.x;
    if (bx < 40) {
        for (int i = bx * 256 + tid; i < n; i += 40 * 256) deg[i] = 0;
    } else if (bx == 40) {
        for (int idx = tid; idx < 128 * 8; idx += 256) {
            int k = idx >> 3, j = idx & 7, h = j & 3;
            const float* av = ((j < 4) ? a_src : a_dst) + h * 64;
            const float* wr = W0 + k * 256 + h * 64;
            float s = 0.f;
#pragma unroll 8
            for (int c = 0; c < 64; ++c) s += wr[c] * av[c];
            wsd0[k * 8 + j] = s;
        }
    } else if (bx <= 43) {
        int l = bx - 41;  // 0..2 -> layers 1..3
        const float* W = (l == 0) ? W1 : (l == 1) ? W2 : W3;
        float* dst = wsdL + l * 64 * 8;
        for (int idx = tid; idx < 64 * 8; idx += 256) {
            int k = idx >> 3, j = idx & 7, h = j & 3;
            const float* av =
                ((j < 4) ? a_src : a_dst) + (l + 1) * 256 + h * 64;
            const float* wr = W + k * 256 + h * 64;
            float s = 0.f;
#pragma unroll 8
            for (int c = 0; c < 64; ++c) s += wr[c] * av[c];
            dst[k * 8 + j] = s;
        }
    } else {
        if (tid < 128)
            bias128[tid] = (tid < 64) ? linB0[tid] : 0.f;
        else if (tid < 192)
            gb0res[tid - 128] = gat_b[tid - 128] + res_b[tid - 128];
    }
}

// ---------------- weight transforms + CSR build + x conversion (merged) -----
__global__ __launch_bounds__(256) void fill_convert(
    const int* __restrict__ ei, int* __restrict__ deg, int* __restrict__ csrS,
    int E, const float* __restrict__ x, const float* __restrict__ wsd0,
    unsigned* __restrict__ xb2, float* __restrict__ Ssrc,
    float* __restrict__ Sdst, int n, int eBlocks,
    const float* __restrict__ W0, const float* __restrict__ W1,
    const float* __restrict__ W2, const float* __restrict__ W3,
    const float* __restrict__ resW, const float* __restrict__ linW0,
    const float* __restrict__ linW1, short* __restrict__ WtC0e,
    short* __restrict__ WtC1, short* __restrict__ WtC2,
    short* __restrict__ WtC3, short* __restrict__ WtUV,
    short* __restrict__ WbT) {
    const int tid = threadIdx.x;
    constexpr int TB = 38;
    if ((int)blockIdx.x < TB) {
        const int bx = blockIdx.x;
        if (bx < 16) {
            for (int s = bx * 256 + tid; s < 40960; s += 16 * 256) {
                if (s < 32768) {
                    int kk = s >> 8, rem = s & 255;
                    int h = rem >> 6, j = rem & 63;
                    WtC0e[j * 640 + h * 128 + kk] = (short)f2b(W0[s]);
                } else {
                    int s2 = s - 32768;
                    int r = s2 >> 6, j = s2 & 63;
                    WtC0e[j * 640 + 512 + r] = (short)f2b(resW[s2]);
                }
            }
        } else if (bx < 32) {
            for (int idx = (bx - 16) * 256 + tid; idx < 3 * 16384;
                 idx += 16 * 256) {
                int w = idx >> 14, s = idx & 16383;
                const float* src = (w == 0) ? W1 : (w == 1) ? W2 : W3;
                short* dst = (w == 0) ? WtC1 : (w == 1) ? WtC2 : WtC3;
                int kk = s >> 8, rem = s & 255;
                int h = rem >> 6, j = rem & 63;
                dst[j * 256 + h * 64 + kk] = (short)f2b(src[s]);
            }
        } else if (bx < 36) {
            for (int s = (bx - 32) * 256 + tid; s < 8192; s += 4 * 256) {
                int K = s >> 6, nn = s & 63;
                WtUV[(K >> 6) * 4096 + nn * 64 + (K & 63)] =
                    (short)f2b(linW0[s]);
            }
        } else {
            for (int s = (bx - 36) * 256 + tid; s < 4096; s += 2 * 256) {
                int k = s >> 6, nn = s & 63;
                WbT[nn * 64 + k] = (short)f2b(linW1[s]);
            }
        }
        return;
    }
    const int bxe = (int)blockIdx.x - TB;
    if (bxe < eBlocks) {
        int e0 = bxe * 2048 + tid * 8;
        if (e0 < E) {  // E % 8 == 0 -> both int4 pairs fully in range
            int4 sa = *(const int4*)(ei + e0);
            int4 sb = *(const int4*)(ei + e0 + 4);
            int4 da = *(const int4*)(ei + E + e0);
            int4 db = *(const int4*)(ei + E + e0 + 4);
            int p0 = atomicAdd(&deg[da.x], 1);
            int p1 = atomicAdd(&deg[da.y], 1);
            int p2 = atomicAdd(&deg[da.z], 1);
            int p3 = atomicAdd(&deg[da.w], 1);
            int p4 = atomicAdd(&deg[db.x], 1);
            int p5 = atomicAdd(&deg[db.y], 1);
            int p6 = atomicAdd(&deg[db.z], 1);
            int p7 = atomicAdd(&deg[db.w], 1);
            if (p0 < MAXDEG) csrS[da.x * MAXDEG + p0] = sa.x;
            if (p1 < MAXDEG) csrS[da.y * MAXDEG + p1] = sa.y;
            if (p2 < MAXDEG) csrS[da.z * MAXDEG + p2] = sa.z;
            if (p3 < MAXDEG) csrS[da.w * MAXDEG + p3] = sa.w;
            if (p4 < MAXDEG) csrS[db.x * MAXDEG + p4] = sb.x;
            if (p5 < MAXDEG) csrS[db.y * MAXDEG + p5] = sb.y;
            if (p6 < MAXDEG) csrS[db.z * MAXDEG + p6] = sb.z;
            if (p7 < MAXDEG) csrS[db.w * MAXDEG + p7] = sb.w;
        }
        return;
    }
    const int nb = bxe - eBlocks;
    const int wid = tid >> 6;
    const int lane = tid & 63;
    const int node = nb * 4 + wid;
    if (node >= n) return;
    float2 xv = *(const float2*)&x[(size_t)node * 128 + lane * 2];
    xb2[(size_t)node * 64 + lane] = packb(xv.x, xv.y);
    float pv[8];
    const float* w0 = &wsd0[(lane * 2) * 8];
    const float* w1 = &wsd0[(lane * 2 + 1) * 8];
#pragma unroll
    for (int j = 0; j < 8; ++j) pv[j] = xv.x * w0[j] + xv.y * w1[j];
#pragma unroll
    for (int off = 1; off < 64; off <<= 1) {
#pragma unroll
        for (int j = 0; j < 8; ++j) pv[j] += __shfl_xor(pv[j], off, 64);
    }
    if (lane == 0) {
        *(float4*)&Ssrc[node * 4] = make_float4(pv[0], pv[1], pv[2], pv[3]);
        *(float4*)&Sdst[node * 4] = make_float4(pv[4], pv[5], pv[6], pv[7]);
    }
}

// ---------------- gather + inline softmax, layer 0 (K=128) ------------------
// qs/sjs slots >= dn hold q=0 / sj=0, so the loop count is rounded up to a
// multiple of 8 (extra iterations add exact zeros) -> clean 8-deep unroll
// batches, 8 feature loads in flight (was 4). Latency-bound loop.
__global__ __launch_bounds__(256) void gat_gather128(
    const int* __restrict__ csrS, const int* __restrict__ deg,
    const float* __restrict__ Ssrc, const float* __restrict__ Sdst,
    const unsigned* __restrict__ xin, unsigned* __restrict__ aggB, int n) {
    __shared__ __align__(16) float qs[4][64][4];
    __shared__ int sjs[4][64];
    const int wid = threadIdx.x >> 6;
    const int lane = threadIdx.x & 63;
    const int node = blockIdx.x * 4 + wid;
    if (node >= n) return;
    const int dn = min(deg[node], MAXDEG);
    const int sreg = (lane < dn) ? csrS[node * MAXDEG + lane] : 0;
    const float4 sd = *(const float4*)&Sdst[node * 4];
    const float4 ss = *(const float4*)&Ssrc[node * 4];
    // self-loop score
    float c0 = ss.x + sd.x, c1 = ss.y + sd.y, c2 = ss.z + sd.z,
          c3 = ss.w + sd.w;
    c0 = c0 > 0.f ? c0 : NSLOPE * c0;
    c1 = c1 > 0.f ? c1 : NSLOPE * c1;
    c2 = c2 > 0.f ? c2 : NSLOPE * c2;
    c3 = c3 > 0.f ? c3 : NSLOPE * c3;
    float ps0 = __expf(c0), ps1 = __expf(c1), ps2 = __expf(c2),
          ps3 = __expf(c3);
    // per-lane edge score (lane p handles CSR slot p)
    float4 sv = *(const float4*)&Ssrc[sreg * 4];
    float e0 = sv.x + sd.x, e1 = sv.y + sd.y;
    float e2 = sv.z + sd.z, e3 = sv.w + sd.w;
    e0 = e0 > 0.f ? e0 : NSLOPE * e0;
    e1 = e1 > 0.f ? e1 : NSLOPE * e1;
    e2 = e2 > 0.f ? e2 : NSLOPE * e2;
    e3 = e3 > 0.f ? e3 : NSLOPE * e3;
    const bool act = lane < dn;
    float q0 = act ? __expf(e0) : 0.f;
    float q1 = act ? __expf(e1) : 0.f;
    float q2 = act ? __expf(e2) : 0.f;
    float q3 = act ? __expf(e3) : 0.f;
    *(float4*)&qs[wid][lane][0] = make_float4(q0, q1, q2, q3);
    sjs[wid][lane] = sreg;
    // z via butterfly over all 64 lanes (masked lanes contribute 0)
    float z0 = q0, z1 = q1, z2 = q2, z3 = q3;
#pragma unroll
    for (int off = 1; off < 64; off <<= 1) {
        z0 += __shfl_xor(z0, off, 64);
        z1 += __shfl_xor(z1, off, 64);
        z2 += __shfl_xor(z2, off, 64);
        z3 += __shfl_xor(z3, off, 64);
    }
    z0 += ps0; z1 += ps1; z2 += ps2; z3 += ps3;
    unsigned own = xin[(size_t)node * 64 + lane];
    float f0o = b2f_lo(own), f1o = b2f_hi(own);
    float u00 = ps0 * f0o, u01 = ps0 * f1o;
    float u10 = ps1 * f0o, u11 = ps1 * f1o;
    float u20 = ps2 * f0o, u21 = ps2 * f1o;
    float u30 = ps3 * f0o, u31 = ps3 * f1o;
    const int dnr = (dn + 7) & ~7;  // <= 64; slots >= dn are zeros
#pragma unroll 8
    for (int p = 0; p < dnr; ++p) {
        float4 qv = *(const float4*)&qs[wid][p][0];
        int sj = sjs[wid][p];
        unsigned fv = xin[(size_t)sj * 64 + lane];
        float f0 = b2f_lo(fv), f1 = b2f_hi(fv);
        u00 += qv.x * f0; u01 += qv.x * f1;
        u10 += qv.y * f0; u11 += qv.y * f1;
        u20 += qv.z * f0; u21 += qv.z * f1;
        u30 += qv.w * f0; u31 += qv.w * f1;
    }
    float i0 = 0.25f / z0, i1 = 0.25f / z1, i2 = 0.25f / z2, i3 = 0.25f / z3;
    size_t base = (size_t)node * 256;
    aggB[base + lane] = packb(u00 * i0, u01 * i0);
    aggB[base + 64 + lane] = packb(u10 * i1, u11 * i1);
    aggB[base + 128 + lane] = packb(u20 * i2, u21 * i2);
    aggB[base + 192 + lane] = packb(u30 * i3, u31 * i3);
}

// ---------------- gather + inline softmax, K=64 (layers 1-3), 2 edges/wave --
// Same rounded-trip-count trick: dnr multiple of 16 -> 8 iterations per half
// per batch, 8 loads in flight.
__global__ __launch_bounds__(256) void gat_gather64(
    const int* __restrict__ csrS, const int* __restrict__ deg,
    const float* __restrict__ Ssrc, const float* __restrict__ Sdst,
    const unsigned* __restrict__ fin, unsigned* __restrict__ aggB, int n) {
    __shared__ __align__(16) float qs[4][64][4];
    __shared__ int sjs[4][64];
    const int wid = threadIdx.x >> 6;
    const int lane = threadIdx.x & 63;
    const int half = lane >> 5;
    const int cl = lane & 31;
    const int node = blockIdx.x * 4 + wid;
    if (node >= n) return;
    const int dn = min(deg[node], MAXDEG);
    const int sreg = (lane < dn) ? csrS[node * MAXDEG + lane] : 0;
    const float4 sd = *(const float4*)&Sdst[node * 4];
    const float4 ss = *(const float4*)&Ssrc[node * 4];
    float c0 = ss.x + sd.x, c1 = ss.y + sd.y, c2 = ss.z + sd.z,
          c3 = ss.w + sd.w;
    c0 = c0 > 0.f ? c0 : NSLOPE * c0;
    c1 = c1 > 0.f ? c1 : NSLOPE * c1;
    c2 = c2 > 0.f ? c2 : NSLOPE * c2;
    c3 = c3 > 0.f ? c3 : NSLOPE * c3;
    float ps0 = __expf(c0), ps1 = __expf(c1), ps2 = __expf(c2),
          ps3 = __expf(c3);
    float4 sv = *(const float4*)&Ssrc[sreg * 4];
    float e0 = sv.x + sd.x, e1 = sv.y + sd.y;
    float e2 = sv.z + sd.z, e3 = sv.w + sd.w;
    e0 = e0 > 0.f ? e0 : NSLOPE * e0;
    e1 = e1 > 0.f ? e1 : NSLOPE * e1;
    e2 = e2 > 0.f ? e2 : NSLOPE * e2;
    e3 = e3 > 0.f ? e3 : NSLOPE * e3;
    const bool act = lane < dn;
    float q0 = act ? __expf(e0) : 0.f;
    float q1 = act ? __expf(e1) : 0.f;
    float q2 = act ? __expf(e2) : 0.f;
    float q3 = act ? __expf(e3) : 0.f;
    *(float4*)&qs[wid][lane][0] = make_float4(q0, q1, q2, q3);
    sjs[wid][lane] = sreg;
    float z0 = q0, z1 = q1, z2 = q2, z3 = q3;
#pragma unroll
    for (int off = 1; off < 64; off <<= 1) {
        z0 += __shfl_xor(z0, off, 64);
        z1 += __shfl_xor(z1, off, 64);
        z2 += __shfl_xor(z2, off, 64);
        z3 += __shfl_xor(z3, off, 64);
    }
    z0 += ps0; z1 += ps1; z2 += ps2; z3 += ps3;
    unsigned own = fin[(size_t)node * 32 + cl];
    float u00 = 0.f, u01 = 0.f, u10 = 0.f, u11 = 0.f;
    float u20 = 0.f, u21 = 0.f, u30 = 0.f, u31 = 0.f;
    const int dnr = (dn + 15) & ~15;  // <= 64; slots >= dn are zeros
#pragma unroll 8
    for (int p = half; p < dnr; p += 2) {
        float4 qv = *(const float4*)&qs[wid][p][0];
        int sj = sjs[wid][p];
        unsigned fv = fin[(size_t)sj * 32 + cl];
        float f0 = b2f_lo(fv), f1 = b2f_hi(fv);
        u00 += qv.x * f0; u01 += qv.x * f1;
        u10 += qv.y * f0; u11 += qv.y * f1;
        u20 += qv.z * f0; u21 += qv.z * f1;
        u30 += qv.w * f0; u31 += qv.w * f1;
    }
    u00 += __shfl_xor(u00, 32, 64); u01 += __shfl_xor(u01, 32, 64);
    u10 += __shfl_xor(u10, 32, 64); u11 += __shfl_xor(u11, 32, 64);
    u20 += __shfl_xor(u20, 32, 64); u21 += __shfl_xor(u21, 32, 64);
    u30 += __shfl_xor(u30, 32, 64); u31 += __shfl_xor(u31, 32, 64);
    // self-loop contribution (all lanes have full sums now)
    float f0o = b2f_lo(own), f1o = b2f_hi(own);
    u00 += ps0 * f0o; u01 += ps0 * f1o;
    u10 += ps1 * f0o; u11 += ps1 * f1o;
    u20 += ps2 * f0o; u21 += ps2 * f1o;
    u30 += ps3 * f0o; u31 += ps3 * f1o;
    float i0 = 0.25f / z0, i1 = 0.25f / z1;
    float i2 = 0.25f / z2, i3 = 0.25f / z3;
    size_t base = (size_t)node * 128;
    if (half == 0) {
        aggB[base + cl] = packb(u00 * i0, u01 * i0);
        aggB[base + 32 + cl] = packb(u10 * i1, u11 * i1);
    } else {
        aggB[base + 64 + cl] = packb(u20 * i2, u21 * i2);
        aggB[base + 96 + cl] = packb(u30 * i3, u31 * i3);
    }
}

// ---------------- layer GEMM (64-row tiles, whole-chunk Ws staging) ---------
template <int KK, int KA, bool SCORES>
__global__ __launch_bounds__(256) void gemm_layer(
    const short* __restrict__ Xb, const short* __restrict__ XbR,
    const short* __restrict__ Wt, const float* __restrict__ gbias,
    const float* __restrict__ resid, const float* __restrict__ wsd,
    float* __restrict__ feat, short* __restrict__ featb,
    float* __restrict__ Ssrc, float* __restrict__ Sdst, int n) {
    __shared__ __align__(16) short Xs[64 * 136];
    __shared__ __align__(16) short Ws[4 * 64 * 40];
    const int tid = threadIdx.x;
    const int nb = blockIdx.x * 64;
    const int wid = tid >> 6;
    const int lane = tid & 63;
    const int t = lane & 15, quad = lane >> 4;
    f32x4 acc[4];
#pragma unroll
    for (int g = 0; g < 4; ++g) acc[g] = (f32x4){0.f, 0.f, 0.f, 0.f};
#pragma unroll 1
    for (int c0 = 0; c0 < KK / 128; ++c0) {
        __syncthreads();
        for (int idx = tid; idx < 1024; idx += 256) {
            int row = idx >> 4, c = idx & 15;
            uint4 v = make_uint4(0, 0, 0, 0);
            if (nb + row < n) {
                if (c0 * 128 < KA)
                    v = *(const uint4*)(Xb + (size_t)(nb + row) * KA +
                                        c0 * 128 + c * 8);
                else
                    v = *(const uint4*)(XbR + (size_t)(nb + row) * 128 + c * 8);
            }
            *(uint4*)(Xs + row * 136 + c * 8) = v;
        }
        for (int idx = tid; idx < 1024; idx += 256) {
            int kcs = idx >> 8, rem = idx & 255;
            int row = rem >> 2, c = rem & 3;
            *(uint4*)(Ws + kcs * 2560 + row * 40 + c * 8) =
                *(const uint4*)(Wt + (size_t)row * KK + c0 * 128 + kcs * 32 +
                                c * 8);
        }
        __syncthreads();
#pragma unroll
        for (int kc = 0; kc < 4; ++kc) {
            bf16x8 a =
                *(const bf16x8*)(Xs + (wid * 16 + t) * 136 + kc * 32 + quad * 8);
#pragma unroll
            for (int g = 0; g < 4; ++g) {
                bf16x8 b = *(const bf16x8*)(Ws + kc * 2560 + (g * 16 + t) * 40 +
                                            quad * 8);
                acc[g] =
                    __builtin_amdgcn_mfma_f32_16x16x32_bf16(a, b, acc[g], 0, 0, 0);
            }
        }
    }
    float bv[4];
#pragma unroll
    for (int g = 0; g < 4; ++g) bv[g] = gbias[g * 16 + t];
    float wsv[4][8];
    if (SCORES) {
#pragma unroll
        for (int g = 0; g < 4; ++g) {
            float4 lo = *(const float4*)&wsd[(g * 16 + t) * 8];
            float4 hi = *(const float4*)&wsd[(g * 16 + t) * 8 + 4];
            wsv[g][0] = lo.x; wsv[g][1] = lo.y; wsv[g][2] = lo.z;
            wsv[g][3] = lo.w; wsv[g][4] = hi.x; wsv[g][5] = hi.y;
            wsv[g][6] = hi.z; wsv[g][7] = hi.w;
        }
    }
#pragma unroll
    for (int r = 0; r < 4; ++r) {
        int node = nb + wid * 16 + quad * 4 + r;
        bool ok = node < n;
        float val[4];
#pragma unroll
        for (int g = 0; g < 4; ++g) {
            float v = acc[g][r] + bv[g];
            if (resid && ok) v += resid[(size_t)node * 64 + g * 16 + t];
            v = v > 0.f ? v : expm1f(v);
            val[g] = v;
            if (ok) {
                feat[(size_t)node * 64 + g * 16 + t] = v;
                featb[(size_t)node * 64 + g * 16 + t] = (short)f2b(v);
            }
        }
        if (SCORES) {
            float pv[8];
#pragma unroll
            for (int j = 0; j < 8; ++j) {
                pv[j] = val[0] * wsv[0][j] + val[1] * wsv[1][j] +
                        val[2] * wsv[2][j] + val[3] * wsv[3][j];
            }
#pragma unroll
            for (int off = 1; off < 16; off <<= 1) {
#pragma unroll
                for (int j = 0; j < 8; ++j) pv[j] += __shfl_xor(pv[j], off, 64);
            }
            if (t == 0 && ok) {
                *(float4*)&Ssrc[node * 4] =
                    make_float4(pv[0], pv[1], pv[2], pv[3]);
                *(float4*)&Sdst[node * 4] =
                    make_float4(pv[4], pv[5], pv[6], pv[7]);
            }
        }
    }
}

// ---------------- layer-3 GEMM fused with UV-heads GEMM ---------------------
__global__ __launch_bounds__(256) void gemm_layer_uv(
    const short* __restrict__ Xb, const short* __restrict__ Wt,
    const float* __restrict__ gbias, const float* __restrict__ resid,
    const short* __restrict__ WtUV, const float* __restrict__ bias128,
    short* __restrict__ OutUV, int n) {
    constexpr int KK = 256;
    __shared__ __align__(16) short Xs[64 * 136];
    __shared__ __align__(16) short Ws[2 * 128 * 40];  // 10240 >= 4*64*40
    const int tid = threadIdx.x;
    const int nb = blockIdx.x * 64;
    const int wid = tid >> 6;
    const int lane = tid & 63;
    const int t = lane & 15, quad = lane >> 4;
    f32x4 acc[4];
#pragma unroll
    for (int g = 0; g < 4; ++g) acc[g] = (f32x4){0.f, 0.f, 0.f, 0.f};
#pragma unroll 1
    for (int c0 = 0; c0 < KK / 128; ++c0) {
        __syncthreads();
        for (int idx = tid; idx < 1024; idx += 256) {
            int row = idx >> 4, c = idx & 15;
            uint4 v = make_uint4(0, 0, 0, 0);
            if (nb + row < n)
                v = *(const uint4*)(Xb + (size_t)(nb + row) * KK + c0 * 128 +
                                    c * 8);
            *(uint4*)(Xs + row * 136 + c * 8) = v;
        }
        for (int idx = tid; idx < 1024; idx += 256) {
            int kcs = idx >> 8, rem = idx & 255;
            int row = rem >> 2, c = rem & 3;
            *(uint4*)(Ws + kcs * 2560 + row * 40 + c * 8) =
                *(const uint4*)(Wt + (size_t)row * KK + c0 * 128 + kcs * 32 +
                                c * 8);
        }
        __syncthreads();
#pragma unroll
        for (int kc = 0; kc < 4; ++kc) {
            bf16x8 a =
                *(const bf16x8*)(Xs + (wid * 16 + t) * 136 + kc * 32 + quad * 8);
#pragma unroll
            for (int g = 0; g < 4; ++g) {
                bf16x8 b = *(const bf16x8*)(Ws + kc * 2560 + (g * 16 + t) * 40 +
                                            quad * 8);
                acc[g] =
                    __builtin_amdgcn_mfma_f32_16x16x32_bf16(a, b, acc[g], 0, 0, 0);
            }
        }
    }
    float bv[4];
#pragma unroll
    for (int g = 0; g < 4; ++g) bv[g] = gbias[g * 16 + t];
    __syncthreads();  // all waves done reading Xs/Ws from the main loop
    // stage whole WtUV as [2 kc][128 rows][40] (one cooperative pass)
    for (int idx = tid; idx < 1024; idx += 256) {
        int kcs = idx >> 9, rem = idx & 511;
        int row = rem >> 2, c = rem & 3;
        *(uint4*)(Ws + kcs * 5120 + row * 40 + c * 8) =
            *(const uint4*)(WtUV + (size_t)row * 64 + kcs * 32 + c * 8);
    }
    // write Hs into Xs region, stride 72 (wave-private rows)
#pragma unroll
    for (int r = 0; r < 4; ++r) {
        int node = nb + wid * 16 + quad * 4 + r;
        bool ok = node < n;
        int lrow = wid * 16 + quad * 4 + r;
#pragma unroll
        for (int g = 0; g < 4; ++g) {
            float v = acc[g][r] + bv[g];
            if (ok) v += resid[(size_t)node * 64 + g * 16 + t];
            v = v > 0.f ? v : expm1f(v);
            Xs[lrow * 72 + g * 16 + t] = (short)f2b(v);
        }
    }
    __syncthreads();  // WtUV staged (Hs reads are wave-private/ordered)
    f32x4 acc2[8];
#pragma unroll
    for (int g = 0; g < 8; ++g) acc2[g] = (f32x4){0.f, 0.f, 0.f, 0.f};
#pragma unroll
    for (int kc = 0; kc < 2; ++kc) {
        bf16x8 a = *(const bf16x8*)(Xs + (wid * 16 + t) * 72 + kc * 32 + quad * 8);
#pragma unroll
        for (int g = 0; g < 8; ++g) {
            bf16x8 b = *(const bf16x8*)(Ws + kc * 5120 + (g * 16 + t) * 40 +
                                        quad * 8);
            acc2[g] = __builtin_amdgcn_mfma_f32_16x16x32_bf16(a, b, acc2[g], 0, 0, 0);
        }
    }
    float b2[8];
#pragma unroll
    for (int g = 0; g < 8; ++g) b2[g] = bias128[g * 16 + t];
#pragma unroll
    for (int r = 0; r < 4; ++r) {
        int node = nb + wid * 16 + quad * 4 + r;
        if (node >= n) continue;
#pragma unroll
        for (int g = 0; g < 8; ++g)
            OutUV[(size_t)node * 128 + g * 16 + t] =
                (short)f2b(acc2[g][r] + b2[g]);
    }
}

// ---------------- edge classifier (MFMA, 64-edge tile) ----------------------
__global__ __launch_bounds__(256) void edge_mlp3(
    const int* __restrict__ ei, const unsigned* __restrict__ UV,
    const short* __restrict__ WbT, const float* __restrict__ bb,
    const float* __restrict__ Wc, const float* __restrict__ bc,
    float* __restrict__ out, int E) {
    __shared__ __align__(16) short t1b[64 * 72];
    __shared__ __align__(16) short wbs[64 * 72];
    const int tid = threadIdx.x;
    const int eBase = blockIdx.x * 64;
    for (int idx = tid; idx < 512; idx += 256) {
        int row = idx >> 3, c = idx & 7;
        *(uint4*)(wbs + row * 72 + c * 8) =
            *(const uint4*)(WbT + row * 64 + c * 8);
    }
    {
        const int j = tid & 31;
        const int eg = tid >> 5;
        int rr[8], cc[8];
#pragma unroll
        for (int it = 0; it < 8; ++it) {
            int e = eBase + it * 8 + eg;
            rr[it] = (e < E) ? ei[e] : 0;
            cc[it] = (e < E) ? ei[E + e] : 0;
        }
#pragma unroll
        for (int it = 0; it < 8; ++it) {
            unsigned uu = UV[(size_t)rr[it] * 64 + j];
            unsigned vv = UV[(size_t)cc[it] * 64 + 32 + j];
            float lo = fmaxf(b2f_lo(uu) + b2f_lo(vv), 0.f);
            float hi = fmaxf(b2f_hi(uu) + b2f_hi(vv), 0.f);
            *(unsigned*)(t1b + (it * 8 + eg) * 72 + j * 2) = packb(lo, hi);
        }
    }
    __syncthreads();
    const int w = tid >> 6, lane = tid & 63;
    const int t = lane & 15, quad = lane >> 4;
    f32x4 acc[4];
#pragma unroll
    for (int g = 0; g < 4; ++g) acc[g] = (f32x4){0.f, 0.f, 0.f, 0.f};
#pragma unroll
    for (int kc = 0; kc < 2; ++kc) {
        bf16x8 a = *(const bf16x8*)(t1b + (w * 16 + t) * 72 + kc * 32 + quad * 8);
#pragma unroll
        for (int g = 0; g < 4; ++g) {
            bf16x8 b = *(const bf16x8*)(wbs + (g * 16 + t) * 72 + kc * 32 + quad * 8);
            acc[g] = __builtin_amdgcn_mfma_f32_16x16x32_bf16(a, b, acc[g], 0, 0, 0);
        }
    }
    float wcv[4], bbv[4];
#pragma unroll
    for (int g = 0; g < 4; ++g) {
        wcv[g] = Wc[g * 16 + t];
        bbv[g] = bb[g * 16 + t];
    }
    const float bcv = bc[0];
#pragma unroll
    for (int r = 0; r < 4; ++r) {
        int el = w * 16 + quad * 4 + r;
        float part = 0.f;
#pragma unroll
        for (int g = 0; g < 4; ++g) {
            float t1v = b2f_s(t1b[el * 72 + g * 16 + t]);
            float t2 = fmaxf(acc[g][r] + bbv[g] + t1v, 0.f);
            part += t2 * wcv[g];
        }
        part += __shfl_xor(part, 1, 64);
        part += __shfl_xor(part, 2, 64);
        part += __shfl_xor(part, 4, 64);
        part += __shfl_xor(part, 8, 64);
        int e = eBase + el;
        if (t == 0 && e < E) out[e] = part + bcv;
    }
}

extern "C" void kernel_launch(void* const* d_in, const int* in_sizes, int n_in,
                              void* d_out, int out_size, void* d_ws,
                              size_t ws_size, hipStream_t stream) {
    const float* x = (const float*)d_in[0];
    const int* ei = (const int*)d_in[1];
    const float* W0 = (const float*)d_in[2];
    const float* W1 = (const float*)d_in[3];
    const float* W2 = (const float*)d_in[4];
    const float* W3 = (const float*)d_in[5];
    const float* a_src = (const float*)d_in[6];
    const float* a_dst = (const float*)d_in[7];
    const float* gat_b = (const float*)d_in[8];
    const float* res_W = (const float*)d_in[9];
    const float* res_b = (const float*)d_in[10];
    const float* lin_W0 = (const float*)d_in[11];
    const float* lin_b0 = (const float*)d_in[12];
    const float* lin_W1 = (const float*)d_in[13];
    const float* lin_b1 = (const float*)d_in[14];
    const float* lin_W2 = (const float*)d_in[15];
    const float* lin_b2 = (const float*)d_in[16];
    float* out = (float*)d_out;

    const int N = in_sizes[0] / 128;  // 20000
    const int E = in_sizes[1] / 2;    // 320000

    char* ws = (char*)d_ws;
    unsigned* aggB = (unsigned*)ws;                    // N*256 u32 (layer0)
    float* featA = (float*)(aggB + (size_t)N * 320);   // N*64
    float* featB = featA + (size_t)N * 64;             // N*64
    unsigned* xb2 = (unsigned*)(featB + (size_t)N * 64);  // N*64 u32
    unsigned* featbA = xb2 + (size_t)N * 64;           // N*32 u32
    unsigned* featbB = featbA + (size_t)N * 32;        // N*32 u32
    unsigned* UVb = featbB + (size_t)N * 32;           // N*64 u32 (dedicated)
    float* Ssrc = (float*)(UVb + (size_t)N * 64);      // N*4
    float* Sdst = Ssrc + (size_t)N * 4;                // N*4
    short* WtC0e = (short*)(Sdst + (size_t)N * 4);     // 64*640
    short* WtC1 = WtC0e + 64 * 640;                    // 64*256
    short* WtC2 = WtC1 + 64 * 256;
    short* WtC3 = WtC2 + 64 * 256;
    short* WtUV = WtC3 + 64 * 256;                     // 128*64
    short* WbT = WtUV + 128 * 64;                      // 64*64
    float* wsd0 = (float*)(WbT + 64 * 64);             // 128*8
    float* wsdL = wsd0 + 128 * 8;                      // 3*64*8
    float* bias128 = wsdL + 3 * 64 * 8;                // 128
    float* gb0res = bias128 + 128;                     // 64
    int* deg = (int*)(gb0res + 64);                    // N
    int* csrS = deg + N;                               // N*MAXDEG

    const int gemmBlocks = (N + 63) / 64;
    const int eBlocks = (E + 2047) / 2048;             // 8 edges/thread
    const int nodeW = (N + 3) / 4;
    const int tBlocks = 38;

    // tiny prep (deg zero + score-weight dots + biases), then merged
    // weight-transforms + CSR build + x conversion
    prep_small<<<45, 256, 0, stream>>>(W0, W1, W2, W3, a_src, a_dst, gat_b,
                                       res_b, lin_b0, wsd0, wsdL, bias128,
                                       gb0res, deg, N);
    fill_convert<<<tBlocks + eBlocks + nodeW, 256, 0, stream>>>(
        ei, deg, csrS, E, x, wsd0, xb2, Ssrc, Sdst, N, eBlocks, W0, W1, W2,
        W3, res_W, lin_W0, lin_W1, WtC0e, WtC1, WtC2, WtC3, WtUV, WbT);

    // layer 0 (residual fold: K=640, A = [aggB 512 | xb2 128])
    gat_gather128<<<nodeW, 256, 0, stream>>>(csrS, deg, Ssrc, Sdst, xb2, aggB,
                                             N);
    gemm_layer<640, 512, true><<<gemmBlocks, 256, 0, stream>>>(
        (const short*)aggB, (const short*)xb2, WtC0e, gb0res, nullptr, wsdL,
        featA, (short*)featbA, Ssrc, Sdst, N);

    // layers 1-2
    gat_gather64<<<nodeW, 256, 0, stream>>>(csrS, deg, Ssrc, Sdst, featbA,
                                            aggB, N);
    gemm_layer<256, 256, true><<<gemmBlocks, 256, 0, stream>>>(
        (const short*)aggB, nullptr, WtC1, gat_b + 64, featA, wsdL + 64 * 8,
        featB, (short*)featbB, Ssrc, Sdst, N);
    gat_gather64<<<nodeW, 256, 0, stream>>>(csrS, deg, Ssrc, Sdst, featbB,
                                            aggB, N);
    gemm_layer<256, 256, true><<<gemmBlocks, 256, 0, stream>>>(
        (const short*)aggB, nullptr, WtC2, gat_b + 128, featB,
        wsdL + 2 * 64 * 8, featA, (short*)featbA, Ssrc, Sdst, N);

    // layer 3 fused with UV heads
    gat_gather64<<<nodeW, 256, 0, stream>>>(csrS, deg, Ssrc, Sdst, featbA,
                                            aggB, N);
    gemm_layer_uv<<<gemmBlocks, 256, 0, stream>>>(
        (const short*)aggB, WtC3, gat_b + 192, featA, WtUV, bias128,
        (short*)UVb, N);

    // edge classifier
    edge_mlp3<<<(E + 63) / 64, 256, 0, stream>>>(ei, UVb, WbT, lin_b1, lin_W2,
                                                 lin_b2, out, E);
}

// Round 13
// 285.306 us; speedup vs baseline: 1.0327x; 1.0327x over previous
//
#include <hip/hip_runtime.h>
#include <hip/hip_bf16.h>

#define NSLOPE 0.2f
#define MAXDEG 64

typedef short bf16x8 __attribute__((ext_vector_type(8)));
typedef float f32x4 __attribute__((ext_vector_type(4)));

__device__ __forceinline__ unsigned short f2b(float f) {
    unsigned u = __float_as_uint(f);
    unsigned r = (u + 0x7FFFu + ((u >> 16) & 1u)) >> 16;
    return (unsigned short)r;
}
__device__ __forceinline__ float b2f_lo(unsigned w) {
    return __uint_as_float(w << 16);
}
__device__ __forceinline__ float b2f_hi(unsigned w) {
    return __uint_as_float(w & 0xFFFF0000u);
}
__device__ __forceinline__ float b2f_s(short s) {
    return __uint_as_float(((unsigned)(unsigned short)s) << 16);
}
__device__ __forceinline__ unsigned packb(float lo, float hi) {
    return ((unsigned)f2b(hi) << 16) | (unsigned)f2b(lo);
}

// ---------------- tiny prep: deg zero + score-weight dots + biases ----------
__global__ __launch_bounds__(256) void prep_small(
    const float* __restrict__ W0, const float* __restrict__ W1,
    const float* __restrict__ W2, const float* __restrict__ W3,
    const float* __restrict__ a_src, const float* __restrict__ a_dst,
    const float* __restrict__ gat_b, const float* __restrict__ res_b,
    const float* __restrict__ linB0, float* __restrict__ wsd0,
    float* __restrict__ wsdL, float* __restrict__ bias128,
    float* __restrict__ gb0res, int* __restrict__ deg, int n) {
    const int bx = blockIdx.x;
    const int tid = threadIdx.x;
    if (bx < 40) {
        for (int i = bx * 256 + tid; i < n; i += 40 * 256) deg[i] = 0;
    } else if (bx == 40) {
        for (int idx = tid; idx < 128 * 8; idx += 256) {
            int k = idx >> 3, j = idx & 7, h = j & 3;
            const float* av = ((j < 4) ? a_src : a_dst) + h * 64;
            const float* wr = W0 + k * 256 + h * 64;
            float s = 0.f;
#pragma unroll 8
            for (int c = 0; c < 64; ++c) s += wr[c] * av[c];
            wsd0[k * 8 + j] = s;
        }
    } else if (bx <= 43) {
        int l = bx - 41;  // 0..2 -> layers 1..3
        const float* W = (l == 0) ? W1 : (l == 1) ? W2 : W3;
        float* dst = wsdL + l * 64 * 8;
        for (int idx = tid; idx < 64 * 8; idx += 256) {
            int k = idx >> 3, j = idx & 7, h = j & 3;
            const float* av =
                ((j < 4) ? a_src : a_dst) + (l + 1) * 256 + h * 64;
            const float* wr = W + k * 256 + h * 64;
            float s = 0.f;
#pragma unroll 8
            for (int c = 0; c < 64; ++c) s += wr[c] * av[c];
            dst[k * 8 + j] = s;
        }
    } else {
        if (tid < 128)
            bias128[tid] = (tid < 64) ? linB0[tid] : 0.f;
        else if (tid < 192)
            gb0res[tid - 128] = gat_b[tid - 128] + res_b[tid - 128];
    }
}

// ---------------- weight transforms + CSR build + x conversion (merged) -----
__global__ __launch_bounds__(256) void fill_convert(
    const int* __restrict__ ei, int* __restrict__ deg, int* __restrict__ csrS,
    int E, const float* __restrict__ x, const float* __restrict__ wsd0,
    unsigned* __restrict__ xb2, float* __restrict__ Ssrc,
    float* __restrict__ Sdst, int n, int eBlocks,
    const float* __restrict__ W0, const float* __restrict__ W1,
    const float* __restrict__ W2, const float* __restrict__ W3,
    const float* __restrict__ resW, const float* __restrict__ linW0,
    const float* __restrict__ linW1, short* __restrict__ WtC0e,
    short* __restrict__ WtC1, short* __restrict__ WtC2,
    short* __restrict__ WtC3, short* __restrict__ WtUV,
    short* __restrict__ WbT) {
    const int tid = threadIdx.x;
    constexpr int TB = 38;
    if ((int)blockIdx.x < TB) {
        const int bx = blockIdx.x;
        if (bx < 16) {
            for (int s = bx * 256 + tid; s < 40960; s += 16 * 256) {
                if (s < 32768) {
                    int kk = s >> 8, rem = s & 255;
                    int h = rem >> 6, j = rem & 63;
                    WtC0e[j * 640 + h * 128 + kk] = (short)f2b(W0[s]);
                } else {
                    int s2 = s - 32768;
                    int r = s2 >> 6, j = s2 & 63;
                    WtC0e[j * 640 + 512 + r] = (short)f2b(resW[s2]);
                }
            }
        } else if (bx < 32) {
            for (int idx = (bx - 16) * 256 + tid; idx < 3 * 16384;
                 idx += 16 * 256) {
                int w = idx >> 14, s = idx & 16383;
                const float* src = (w == 0) ? W1 : (w == 1) ? W2 : W3;
                short* dst = (w == 0) ? WtC1 : (w == 1) ? WtC2 : WtC3;
                int kk = s >> 8, rem = s & 255;
                int h = rem >> 6, j = rem & 63;
                dst[j * 256 + h * 64 + kk] = (short)f2b(src[s]);
            }
        } else if (bx < 36) {
            for (int s = (bx - 32) * 256 + tid; s < 8192; s += 4 * 256) {
                int K = s >> 6, nn = s & 63;
                WtUV[(K >> 6) * 4096 + nn * 64 + (K & 63)] =
                    (short)f2b(linW0[s]);
            }
        } else {
            for (int s = (bx - 36) * 256 + tid; s < 4096; s += 2 * 256) {
                int k = s >> 6, nn = s & 63;
                WbT[nn * 64 + k] = (short)f2b(linW1[s]);
            }
        }
        return;
    }
    const int bxe = (int)blockIdx.x - TB;
    if (bxe < eBlocks) {
        int e0 = bxe * 2048 + tid * 8;
        if (e0 < E) {  // E % 8 == 0 -> both int4 pairs fully in range
            int4 sa = *(const int4*)(ei + e0);
            int4 sb = *(const int4*)(ei + e0 + 4);
            int4 da = *(const int4*)(ei + E + e0);
            int4 db = *(const int4*)(ei + E + e0 + 4);
            int p0 = atomicAdd(&deg[da.x], 1);
            int p1 = atomicAdd(&deg[da.y], 1);
            int p2 = atomicAdd(&deg[da.z], 1);
            int p3 = atomicAdd(&deg[da.w], 1);
            int p4 = atomicAdd(&deg[db.x], 1);
            int p5 = atomicAdd(&deg[db.y], 1);
            int p6 = atomicAdd(&deg[db.z], 1);
            int p7 = atomicAdd(&deg[db.w], 1);
            if (p0 < MAXDEG) csrS[da.x * MAXDEG + p0] = sa.x;
            if (p1 < MAXDEG) csrS[da.y * MAXDEG + p1] = sa.y;
            if (p2 < MAXDEG) csrS[da.z * MAXDEG + p2] = sa.z;
            if (p3 < MAXDEG) csrS[da.w * MAXDEG + p3] = sa.w;
            if (p4 < MAXDEG) csrS[db.x * MAXDEG + p4] = sb.x;
            if (p5 < MAXDEG) csrS[db.y * MAXDEG + p5] = sb.y;
            if (p6 < MAXDEG) csrS[db.z * MAXDEG + p6] = sb.z;
            if (p7 < MAXDEG) csrS[db.w * MAXDEG + p7] = sb.w;
        }
        return;
    }
    const int nb = bxe - eBlocks;
    const int wid = tid >> 6;
    const int lane = tid & 63;
    const int node = nb * 4 + wid;
    if (node >= n) return;
    float2 xv = *(const float2*)&x[(size_t)node * 128 + lane * 2];
    xb2[(size_t)node * 64 + lane] = packb(xv.x, xv.y);
    float pv[8];
    const float* w0 = &wsd0[(lane * 2) * 8];
    const float* w1 = &wsd0[(lane * 2 + 1) * 8];
#pragma unroll
    for (int j = 0; j < 8; ++j) pv[j] = xv.x * w0[j] + xv.y * w1[j];
#pragma unroll
    for (int off = 1; off < 64; off <<= 1) {
#pragma unroll
        for (int j = 0; j < 8; ++j) pv[j] += __shfl_xor(pv[j], off, 64);
    }
    if (lane == 0) {
        *(float4*)&Ssrc[node * 4] = make_float4(pv[0], pv[1], pv[2], pv[3]);
        *(float4*)&Sdst[node * 4] = make_float4(pv[4], pv[5], pv[6], pv[7]);
    }
}

// ---------------- gather + inline softmax, layer 0 (K=128) ------------------
// Lane-parallel edge scores (lane p scores edge p, 4 exps/lane once), stashed
// in wave-private LDS; z via 64-lane butterfly. Exact trip count, unroll 4 —
// best measured (ILP widening/deepening both regressed: R4, R12).
__global__ __launch_bounds__(256) void gat_gather128(
    const int* __restrict__ csrS, const int* __restrict__ deg,
    const float* __restrict__ Ssrc, const float* __restrict__ Sdst,
    const unsigned* __restrict__ xin, unsigned* __restrict__ aggB, int n) {
    __shared__ __align__(16) float qs[4][64][4];
    __shared__ int sjs[4][64];
    const int wid = threadIdx.x >> 6;
    const int lane = threadIdx.x & 63;
    const int node = blockIdx.x * 4 + wid;
    if (node >= n) return;
    const int dn = min(deg[node], MAXDEG);
    const int sreg = (lane < dn) ? csrS[node * MAXDEG + lane] : 0;
    const float4 sd = *(const float4*)&Sdst[node * 4];
    const float4 ss = *(const float4*)&Ssrc[node * 4];
    // self-loop score
    float c0 = ss.x + sd.x, c1 = ss.y + sd.y, c2 = ss.z + sd.z,
          c3 = ss.w + sd.w;
    c0 = c0 > 0.f ? c0 : NSLOPE * c0;
    c1 = c1 > 0.f ? c1 : NSLOPE * c1;
    c2 = c2 > 0.f ? c2 : NSLOPE * c2;
    c3 = c3 > 0.f ? c3 : NSLOPE * c3;
    float ps0 = __expf(c0), ps1 = __expf(c1), ps2 = __expf(c2),
          ps3 = __expf(c3);
    // per-lane edge score (lane p handles CSR slot p)
    float4 sv = *(const float4*)&Ssrc[sreg * 4];
    float e0 = sv.x + sd.x, e1 = sv.y + sd.y;
    float e2 = sv.z + sd.z, e3 = sv.w + sd.w;
    e0 = e0 > 0.f ? e0 : NSLOPE * e0;
    e1 = e1 > 0.f ? e1 : NSLOPE * e1;
    e2 = e2 > 0.f ? e2 : NSLOPE * e2;
    e3 = e3 > 0.f ? e3 : NSLOPE * e3;
    const bool act = lane < dn;
    float q0 = act ? __expf(e0) : 0.f;
    float q1 = act ? __expf(e1) : 0.f;
    float q2 = act ? __expf(e2) : 0.f;
    float q3 = act ? __expf(e3) : 0.f;
    *(float4*)&qs[wid][lane][0] = make_float4(q0, q1, q2, q3);
    sjs[wid][lane] = sreg;
    // z via butterfly over all 64 lanes (masked lanes contribute 0)
    float z0 = q0, z1 = q1, z2 = q2, z3 = q3;
#pragma unroll
    for (int off = 1; off < 64; off <<= 1) {
        z0 += __shfl_xor(z0, off, 64);
        z1 += __shfl_xor(z1, off, 64);
        z2 += __shfl_xor(z2, off, 64);
        z3 += __shfl_xor(z3, off, 64);
    }
    z0 += ps0; z1 += ps1; z2 += ps2; z3 += ps3;
    unsigned own = xin[(size_t)node * 64 + lane];
    float f0o = b2f_lo(own), f1o = b2f_hi(own);
    float u00 = ps0 * f0o, u01 = ps0 * f1o;
    float u10 = ps1 * f0o, u11 = ps1 * f1o;
    float u20 = ps2 * f0o, u21 = ps2 * f1o;
    float u30 = ps3 * f0o, u31 = ps3 * f1o;
#pragma unroll 4
    for (int p = 0; p < dn; ++p) {
        float4 qv = *(const float4*)&qs[wid][p][0];
        int sj = sjs[wid][p];
        unsigned fv = xin[(size_t)sj * 64 + lane];
        float f0 = b2f_lo(fv), f1 = b2f_hi(fv);
        u00 += qv.x * f0; u01 += qv.x * f1;
        u10 += qv.y * f0; u11 += qv.y * f1;
        u20 += qv.z * f0; u21 += qv.z * f1;
        u30 += qv.w * f0; u31 += qv.w * f1;
    }
    float i0 = 0.25f / z0, i1 = 0.25f / z1, i2 = 0.25f / z2, i3 = 0.25f / z3;
    size_t base = (size_t)node * 256;
    aggB[base + lane] = packb(u00 * i0, u01 * i0);
    aggB[base + 64 + lane] = packb(u10 * i1, u11 * i1);
    aggB[base + 128 + lane] = packb(u20 * i2, u21 * i2);
    aggB[base + 192 + lane] = packb(u30 * i3, u31 * i3);
}

// ---------------- gather + inline softmax, K=64 (layers 1-3), 2 edges/wave --
__global__ __launch_bounds__(256) void gat_gather64(
    const int* __restrict__ csrS, const int* __restrict__ deg,
    const float* __restrict__ Ssrc, const float* __restrict__ Sdst,
    const unsigned* __restrict__ fin, unsigned* __restrict__ aggB, int n) {
    __shared__ __align__(16) float qs[4][64][4];
    __shared__ int sjs[4][64];
    const int wid = threadIdx.x >> 6;
    const int lane = threadIdx.x & 63;
    const int half = lane >> 5;
    const int cl = lane & 31;
    const int node = blockIdx.x * 4 + wid;
    if (node >= n) return;
    const int dn = min(deg[node], MAXDEG);
    const int sreg = (lane < dn) ? csrS[node * MAXDEG + lane] : 0;
    const float4 sd = *(const float4*)&Sdst[node * 4];
    const float4 ss = *(const float4*)&Ssrc[node * 4];
    float c0 = ss.x + sd.x, c1 = ss.y + sd.y, c2 = ss.z + sd.z,
          c3 = ss.w + sd.w;
    c0 = c0 > 0.f ? c0 : NSLOPE * c0;
    c1 = c1 > 0.f ? c1 : NSLOPE * c1;
    c2 = c2 > 0.f ? c2 : NSLOPE * c2;
    c3 = c3 > 0.f ? c3 : NSLOPE * c3;
    float ps0 = __expf(c0), ps1 = __expf(c1), ps2 = __expf(c2),
          ps3 = __expf(c3);
    float4 sv = *(const float4*)&Ssrc[sreg * 4];
    float e0 = sv.x + sd.x, e1 = sv.y + sd.y;
    float e2 = sv.z + sd.z, e3 = sv.w + sd.w;
    e0 = e0 > 0.f ? e0 : NSLOPE * e0;
    e1 = e1 > 0.f ? e1 : NSLOPE * e1;
    e2 = e2 > 0.f ? e2 : NSLOPE * e2;
    e3 = e3 > 0.f ? e3 : NSLOPE * e3;
    const bool act = lane < dn;
    float q0 = act ? __expf(e0) : 0.f;
    float q1 = act ? __expf(e1) : 0.f;
    float q2 = act ? __expf(e2) : 0.f;
    float q3 = act ? __expf(e3) : 0.f;
    *(float4*)&qs[wid][lane][0] = make_float4(q0, q1, q2, q3);
    sjs[wid][lane] = sreg;
    float z0 = q0, z1 = q1, z2 = q2, z3 = q3;
#pragma unroll
    for (int off = 1; off < 64; off <<= 1) {
        z0 += __shfl_xor(z0, off, 64);
        z1 += __shfl_xor(z1, off, 64);
        z2 += __shfl_xor(z2, off, 64);
        z3 += __shfl_xor(z3, off, 64);
    }
    z0 += ps0; z1 += ps1; z2 += ps2; z3 += ps3;
    unsigned own = fin[(size_t)node * 32 + cl];
    float u00 = 0.f, u01 = 0.f, u10 = 0.f, u11 = 0.f;
    float u20 = 0.f, u21 = 0.f, u30 = 0.f, u31 = 0.f;
#pragma unroll 4
    for (int p = half; p < dn; p += 2) {
        float4 qv = *(const float4*)&qs[wid][p][0];
        int sj = sjs[wid][p];
        unsigned fv = fin[(size_t)sj * 32 + cl];
        float f0 = b2f_lo(fv), f1 = b2f_hi(fv);
        u00 += qv.x * f0; u01 += qv.x * f1;
        u10 += qv.y * f0; u11 += qv.y * f1;
        u20 += qv.z * f0; u21 += qv.z * f1;
        u30 += qv.w * f0; u31 += qv.w * f1;
    }
    u00 += __shfl_xor(u00, 32, 64); u01 += __shfl_xor(u01, 32, 64);
    u10 += __shfl_xor(u10, 32, 64); u11 += __shfl_xor(u11, 32, 64);
    u20 += __shfl_xor(u20, 32, 64); u21 += __shfl_xor(u21, 32, 64);
    u30 += __shfl_xor(u30, 32, 64); u31 += __shfl_xor(u31, 32, 64);
    // self-loop contribution (all lanes have full sums now)
    float f0o = b2f_lo(own), f1o = b2f_hi(own);
    u00 += ps0 * f0o; u01 += ps0 * f1o;
    u10 += ps1 * f0o; u11 += ps1 * f1o;
    u20 += ps2 * f0o; u21 += ps2 * f1o;
    u30 += ps3 * f0o; u31 += ps3 * f1o;
    float i0 = 0.25f / z0, i1 = 0.25f / z1;
    float i2 = 0.25f / z2, i3 = 0.25f / z3;
    size_t base = (size_t)node * 128;
    if (half == 0) {
        aggB[base + cl] = packb(u00 * i0, u01 * i0);
        aggB[base + 32 + cl] = packb(u10 * i1, u11 * i1);
    } else {
        aggB[base + 64 + cl] = packb(u20 * i2, u21 * i2);
        aggB[base + 96 + cl] = packb(u30 * i3, u31 * i3);
    }
}

// ---------------- layer GEMM (64-row tiles, whole-chunk Ws staging) ---------
template <int KK, int KA, bool SCORES>
__global__ __launch_bounds__(256) void gemm_layer(
    const short* __restrict__ Xb, const short* __restrict__ XbR,
    const short* __restrict__ Wt, const float* __restrict__ gbias,
    const float* __restrict__ resid, const float* __restrict__ wsd,
    float* __restrict__ feat, short* __restrict__ featb,
    float* __restrict__ Ssrc, float* __restrict__ Sdst, int n) {
    __shared__ __align__(16) short Xs[64 * 136];
    __shared__ __align__(16) short Ws[4 * 64 * 40];
    const int tid = threadIdx.x;
    const int nb = blockIdx.x * 64;
    const int wid = tid >> 6;
    const int lane = tid & 63;
    const int t = lane & 15, quad = lane >> 4;
    f32x4 acc[4];
#pragma unroll
    for (int g = 0; g < 4; ++g) acc[g] = (f32x4){0.f, 0.f, 0.f, 0.f};
#pragma unroll 1
    for (int c0 = 0; c0 < KK / 128; ++c0) {
        __syncthreads();
        for (int idx = tid; idx < 1024; idx += 256) {
            int row = idx >> 4, c = idx & 15;
            uint4 v = make_uint4(0, 0, 0, 0);
            if (nb + row < n) {
                if (c0 * 128 < KA)
                    v = *(const uint4*)(Xb + (size_t)(nb + row) * KA +
                                        c0 * 128 + c * 8);
                else
                    v = *(const uint4*)(XbR + (size_t)(nb + row) * 128 + c * 8);
            }
            *(uint4*)(Xs + row * 136 + c * 8) = v;
        }
        for (int idx = tid; idx < 1024; idx += 256) {
            int kcs = idx >> 8, rem = idx & 255;
            int row = rem >> 2, c = rem & 3;
            *(uint4*)(Ws + kcs * 2560 + row * 40 + c * 8) =
                *(const uint4*)(Wt + (size_t)row * KK + c0 * 128 + kcs * 32 +
                                c * 8);
        }
        __syncthreads();
#pragma unroll
        for (int kc = 0; kc < 4; ++kc) {
            bf16x8 a =
                *(const bf16x8*)(Xs + (wid * 16 + t) * 136 + kc * 32 + quad * 8);
#pragma unroll
            for (int g = 0; g < 4; ++g) {
                bf16x8 b = *(const bf16x8*)(Ws + kc * 2560 + (g * 16 + t) * 40 +
                                            quad * 8);
                acc[g] =
                    __builtin_amdgcn_mfma_f32_16x16x32_bf16(a, b, acc[g], 0, 0, 0);
            }
        }
    }
    float bv[4];
#pragma unroll
    for (int g = 0; g < 4; ++g) bv[g] = gbias[g * 16 + t];
    float wsv[4][8];
    if (SCORES) {
#pragma unroll
        for (int g = 0; g < 4; ++g) {
            float4 lo = *(const float4*)&wsd[(g * 16 + t) * 8];
            float4 hi = *(const float4*)&wsd[(g * 16 + t) * 8 + 4];
            wsv[g][0] = lo.x; wsv[g][1] = lo.y; wsv[g][2] = lo.z;
            wsv[g][3] = lo.w; wsv[g][4] = hi.x; wsv[g][5] = hi.y;
            wsv[g][6] = hi.z; wsv[g][7] = hi.w;
        }
    }
#pragma unroll
    for (int r = 0; r < 4; ++r) {
        int node = nb + wid * 16 + quad * 4 + r;
        bool ok = node < n;
        float val[4];
#pragma unroll
        for (int g = 0; g < 4; ++g) {
            float v = acc[g][r] + bv[g];
            if (resid && ok) v += resid[(size_t)node * 64 + g * 16 + t];
            v = v > 0.f ? v : expm1f(v);
            val[g] = v;
            if (ok) {
                feat[(size_t)node * 64 + g * 16 + t] = v;
                featb[(size_t)node * 64 + g * 16 + t] = (short)f2b(v);
            }
        }
        if (SCORES) {
            float pv[8];
#pragma unroll
            for (int j = 0; j < 8; ++j) {
                pv[j] = val[0] * wsv[0][j] + val[1] * wsv[1][j] +
                        val[2] * wsv[2][j] + val[3] * wsv[3][j];
            }
#pragma unroll
            for (int off = 1; off < 16; off <<= 1) {
#pragma unroll
                for (int j = 0; j < 8; ++j) pv[j] += __shfl_xor(pv[j], off, 64);
            }
            if (t == 0 && ok) {
                *(float4*)&Ssrc[node * 4] =
                    make_float4(pv[0], pv[1], pv[2], pv[3]);
                *(float4*)&Sdst[node * 4] =
                    make_float4(pv[4], pv[5], pv[6], pv[7]);
            }
        }
    }
}

// ---------------- layer-3 GEMM fused with UV-heads GEMM ---------------------
__global__ __launch_bounds__(256) void gemm_layer_uv(
    const short* __restrict__ Xb, const short* __restrict__ Wt,
    const float* __restrict__ gbias, const float* __restrict__ resid,
    const short* __restrict__ WtUV, const float* __restrict__ bias128,
    short* __restrict__ OutUV, int n) {
    constexpr int KK = 256;
    __shared__ __align__(16) short Xs[64 * 136];
    __shared__ __align__(16) short Ws[2 * 128 * 40];  // 10240 >= 4*64*40
    const int tid = threadIdx.x;
    const int nb = blockIdx.x * 64;
    const int wid = tid >> 6;
    const int lane = tid & 63;
    const int t = lane & 15, quad = lane >> 4;
    f32x4 acc[4];
#pragma unroll
    for (int g = 0; g < 4; ++g) acc[g] = (f32x4){0.f, 0.f, 0.f, 0.f};
#pragma unroll 1
    for (int c0 = 0; c0 < KK / 128; ++c0) {
        __syncthreads();
        for (int idx = tid; idx < 1024; idx += 256) {
            int row = idx >> 4, c = idx & 15;
            uint4 v = make_uint4(0, 0, 0, 0);
            if (nb + row < n)
                v = *(const uint4*)(Xb + (size_t)(nb + row) * KK + c0 * 128 +
                                    c * 8);
            *(uint4*)(Xs + row * 136 + c * 8) = v;
        }
        for (int idx = tid; idx < 1024; idx += 256) {
            int kcs = idx >> 8, rem = idx & 255;
            int row = rem >> 2, c = rem & 3;
            *(uint4*)(Ws + kcs * 2560 + row * 40 + c * 8) =
                *(const uint4*)(Wt + (size_t)row * KK + c0 * 128 + kcs * 32 +
                                c * 8);
        }
        __syncthreads();
#pragma unroll
        for (int kc = 0; kc < 4; ++kc) {
            bf16x8 a =
                *(const bf16x8*)(Xs + (wid * 16 + t) * 136 + kc * 32 + quad * 8);
#pragma unroll
            for (int g = 0; g < 4; ++g) {
                bf16x8 b = *(const bf16x8*)(Ws + kc * 2560 + (g * 16 + t) * 40 +
                                            quad * 8);
                acc[g] =
                    __builtin_amdgcn_mfma_f32_16x16x32_bf16(a, b, acc[g], 0, 0, 0);
            }
        }
    }
    float bv[4];
#pragma unroll
    for (int g = 0; g < 4; ++g) bv[g] = gbias[g * 16 + t];
    __syncthreads();  // all waves done reading Xs/Ws from the main loop
    // stage whole WtUV as [2 kc][128 rows][40] (one cooperative pass)
    for (int idx = tid; idx < 1024; idx += 256) {
        int kcs = idx >> 9, rem = idx & 511;
        int row = rem >> 2, c = rem & 3;
        *(uint4*)(Ws + kcs * 5120 + row * 40 + c * 8) =
            *(const uint4*)(WtUV + (size_t)row * 64 + kcs * 32 + c * 8);
    }
    // write Hs into Xs region, stride 72 (wave-private rows)
#pragma unroll
    for (int r = 0; r < 4; ++r) {
        int node = nb + wid * 16 + quad * 4 + r;
        bool ok = node < n;
        int lrow = wid * 16 + quad * 4 + r;
#pragma unroll
        for (int g = 0; g < 4; ++g) {
            float v = acc[g][r] + bv[g];
            if (ok) v += resid[(size_t)node * 64 + g * 16 + t];
            v = v > 0.f ? v : expm1f(v);
            Xs[lrow * 72 + g * 16 + t] = (short)f2b(v);
        }
    }
    __syncthreads();  // WtUV staged (Hs reads are wave-private/ordered)
    f32x4 acc2[8];
#pragma unroll
    for (int g = 0; g < 8; ++g) acc2[g] = (f32x4){0.f, 0.f, 0.f, 0.f};
#pragma unroll
    for (int kc = 0; kc < 2; ++kc) {
        bf16x8 a = *(const bf16x8*)(Xs + (wid * 16 + t) * 72 + kc * 32 + quad * 8);
#pragma unroll
        for (int g = 0; g < 8; ++g) {
            bf16x8 b = *(const bf16x8*)(Ws + kc * 5120 + (g * 16 + t) * 40 +
                                        quad * 8);
            acc2[g] = __builtin_amdgcn_mfma_f32_16x16x32_bf16(a, b, acc2[g], 0, 0, 0);
        }
    }
    float b2[8];
#pragma unroll
    for (int g = 0; g < 8; ++g) b2[g] = bias128[g * 16 + t];
#pragma unroll
    for (int r = 0; r < 4; ++r) {
        int node = nb + wid * 16 + quad * 4 + r;
        if (node >= n) continue;
#pragma unroll
        for (int g = 0; g < 8; ++g)
            OutUV[(size_t)node * 128 + g * 16 + t] =
                (short)f2b(acc2[g][r] + b2[g]);
    }
}

// ---------------- edge classifier (MFMA, 64-edge tile) ----------------------
__global__ __launch_bounds__(256) void edge_mlp3(
    const int* __restrict__ ei, const unsigned* __restrict__ UV,
    const short* __restrict__ WbT, const float* __restrict__ bb,
    const float* __restrict__ Wc, const float* __restrict__ bc,
    float* __restrict__ out, int E) {
    __shared__ __align__(16) short t1b[64 * 72];
    __shared__ __align__(16) short wbs[64 * 72];
    const int tid = threadIdx.x;
    const int eBase = blockIdx.x * 64;
    for (int idx = tid; idx < 512; idx += 256) {
        int row = idx >> 3, c = idx & 7;
        *(uint4*)(wbs + row * 72 + c * 8) =
            *(const uint4*)(WbT + row * 64 + c * 8);
    }
    {
        const int j = tid & 31;
        const int eg = tid >> 5;
        int rr[8], cc[8];
#pragma unroll
        for (int it = 0; it < 8; ++it) {
            int e = eBase + it * 8 + eg;
            rr[it] = (e < E) ? ei[e] : 0;
            cc[it] = (e < E) ? ei[E + e] : 0;
        }
#pragma unroll
        for (int it = 0; it < 8; ++it) {
            unsigned uu = UV[(size_t)rr[it] * 64 + j];
            unsigned vv = UV[(size_t)cc[it] * 64 + 32 + j];
            float lo = fmaxf(b2f_lo(uu) + b2f_lo(vv), 0.f);
            float hi = fmaxf(b2f_hi(uu) + b2f_hi(vv), 0.f);
            *(unsigned*)(t1b + (it * 8 + eg) * 72 + j * 2) = packb(lo, hi);
        }
    }
    __syncthreads();
    const int w = tid >> 6, lane = tid & 63;
    const int t = lane & 15, quad = lane >> 4;
    f32x4 acc[4];
#pragma unroll
    for (int g = 0; g < 4; ++g) acc[g] = (f32x4){0.f, 0.f, 0.f, 0.f};
#pragma unroll
    for (int kc = 0; kc < 2; ++kc) {
        bf16x8 a = *(const bf16x8*)(t1b + (w * 16 + t) * 72 + kc * 32 + quad * 8);
#pragma unroll
        for (int g = 0; g < 4; ++g) {
            bf16x8 b = *(const bf16x8*)(wbs + (g * 16 + t) * 72 + kc * 32 + quad * 8);
            acc[g] = __builtin_amdgcn_mfma_f32_16x16x32_bf16(a, b, acc[g], 0, 0, 0);
        }
    }
    float wcv[4], bbv[4];
#pragma unroll
    for (int g = 0; g < 4; ++g) {
        wcv[g] = Wc[g * 16 + t];
        bbv[g] = bb[g * 16 + t];
    }
    const float bcv = bc[0];
#pragma unroll
    for (int r = 0; r < 4; ++r) {
        int el = w * 16 + quad * 4 + r;
        float part = 0.f;
#pragma unroll
        for (int g = 0; g < 4; ++g) {
            float t1v = b2f_s(t1b[el * 72 + g * 16 + t]);
            float t2 = fmaxf(acc[g][r] + bbv[g] + t1v, 0.f);
            part += t2 * wcv[g];
        }
        part += __shfl_xor(part, 1, 64);
        part += __shfl_xor(part, 2, 64);
        part += __shfl_xor(part, 4, 64);
        part += __shfl_xor(part, 8, 64);
        int e = eBase + el;
        if (t == 0 && e < E) out[e] = part + bcv;
    }
}

extern "C" void kernel_launch(void* const* d_in, const int* in_sizes, int n_in,
                              void* d_out, int out_size, void* d_ws,
                              size_t ws_size, hipStream_t stream) {
    const float* x = (const float*)d_in[0];
    const int* ei = (const int*)d_in[1];
    const float* W0 = (const float*)d_in[2];
    const float* W1 = (const float*)d_in[3];
    const float* W2 = (const float*)d_in[4];
    const float* W3 = (const float*)d_in[5];
    const float* a_src = (const float*)d_in[6];
    const float* a_dst = (const float*)d_in[7];
    const float* gat_b = (const float*)d_in[8];
    const float* res_W = (const float*)d_in[9];
    const float* res_b = (const float*)d_in[10];
    const float* lin_W0 = (const float*)d_in[11];
    const float* lin_b0 = (const float*)d_in[12];
    const float* lin_W1 = (const float*)d_in[13];
    const float* lin_b1 = (const float*)d_in[14];
    const float* lin_W2 = (const float*)d_in[15];
    const float* lin_b2 = (const float*)d_in[16];
    float* out = (float*)d_out;

    const int N = in_sizes[0] / 128;  // 20000
    const int E = in_sizes[1] / 2;    // 320000

    char* ws = (char*)d_ws;
    unsigned* aggB = (unsigned*)ws;                    // N*256 u32 (layer0)
    float* featA = (float*)(aggB + (size_t)N * 320);   // N*64
    float* featB = featA + (size_t)N * 64;             // N*64
    unsigned* xb2 = (unsigned*)(featB + (size_t)N * 64);  // N*64 u32
    unsigned* featbA = xb2 + (size_t)N * 64;           // N*32 u32
    unsigned* featbB = featbA + (size_t)N * 32;        // N*32 u32
    unsigned* UVb = featbB + (size_t)N * 32;           // N*64 u32 (dedicated)
    float* Ssrc = (float*)(UVb + (size_t)N * 64);      // N*4
    float* Sdst = Ssrc + (size_t)N * 4;                // N*4
    short* WtC0e = (short*)(Sdst + (size_t)N * 4);     // 64*640
    short* WtC1 = WtC0e + 64 * 640;                    // 64*256
    short* WtC2 = WtC1 + 64 * 256;
    short* WtC3 = WtC2 + 64 * 256;
    short* WtUV = WtC3 + 64 * 256;                     // 128*64
    short* WbT = WtUV + 128 * 64;                      // 64*64
    float* wsd0 = (float*)(WbT + 64 * 64);             // 128*8
    float* wsdL = wsd0 + 128 * 8;                      // 3*64*8
    float* bias128 = wsdL + 3 * 64 * 8;                // 128
    float* gb0res = bias128 + 128;                     // 64
    int* deg = (int*)(gb0res + 64);                    // N
    int* csrS = deg + N;                               // N*MAXDEG

    const int gemmBlocks = (N + 63) / 64;
    const int eBlocks = (E + 2047) / 2048;             // 8 edges/thread
    const int nodeW = (N + 3) / 4;
    const int tBlocks = 38;

    // tiny prep (deg zero + score-weight dots + biases), then merged
    // weight-transforms + CSR build + x conversion
    prep_small<<<45, 256, 0, stream>>>(W0, W1, W2, W3, a_src, a_dst, gat_b,
                                       res_b, lin_b0, wsd0, wsdL, bias128,
                                       gb0res, deg, N);
    fill_convert<<<tBlocks + eBlocks + nodeW, 256, 0, stream>>>(
        ei, deg, csrS, E, x, wsd0, xb2, Ssrc, Sdst, N, eBlocks, W0, W1, W2,
        W3, res_W, lin_W0, lin_W1, WtC0e, WtC1, WtC2, WtC3, WtUV, WbT);

    // layer 0 (residual fold: K=640, A = [aggB 512 | xb2 128])
    gat_gather128<<<nodeW, 256, 0, stream>>>(csrS, deg, Ssrc, Sdst, xb2, aggB,
                                             N);
    gemm_layer<640, 512, true><<<gemmBlocks, 256, 0, stream>>>(
        (const short*)aggB, (const short*)xb2, WtC0e, gb0res, nullptr, wsdL,
        featA, (short*)featbA, Ssrc, Sdst, N);

    // layers 1-2
    gat_gather64<<<nodeW, 256, 0, stream>>>(csrS, deg, Ssrc, Sdst, featbA,
                                            aggB, N);
    gemm_layer<256, 256, true><<<gemmBlocks, 256, 0, stream>>>(
        (const short*)aggB, nullptr, WtC1, gat_b + 64, featA, wsdL + 64 * 8,
        featB, (short*)featbB, Ssrc, Sdst, N);
    gat_gather64<<<nodeW, 256, 0, stream>>>(csrS, deg, Ssrc, Sdst, featbB,
                                            aggB, N);
    gemm_layer<256, 256, true><<<gemmBlocks, 256, 0, stream>>>(
        (const short*)aggB, nullptr, WtC2, gat_b + 128, featB,
        wsdL + 2 * 64 * 8, featA, (short*)featbA, Ssrc, Sdst, N);

    // layer 3 fused with UV heads
    gat_gather64<<<nodeW, 256, 0, stream>>>(csrS, deg, Ssrc, Sdst, featbA,
                                            aggB, N);
    gemm_layer_uv<<<gemmBlocks, 256, 0, stream>>>(
        (const short*)aggB, WtC3, gat_b + 192, featA, WtUV, bias128,
        (short*)UVb, N);

    // edge classifier
    edge_mlp3<<<(E + 63) / 64, 256, 0, stream>>>(ei, UVb, WbT, lin_b1, lin_W2,
                                                 lin_b2, out, E);
}